// Round 5
// baseline (1475.110 us; speedup 1.0000x reference)
//
#include <hip/hip_runtime.h>
#include <cstdint>
#include <cstddef>

#define NNODES 50000
#define HD 256
#define NCH 3
#define BM 64

typedef __attribute__((ext_vector_type(8))) short shortx8;
typedef __attribute__((ext_vector_type(4))) float floatx4;

__device__ __forceinline__ unsigned short f2bf(float x) {
    union { float f; uint32_t u; } v; v.f = x;
    uint32_t r = v.u + 0x7fffu + ((v.u >> 16) & 1u);   // round-to-nearest-even
    return (unsigned short)(r >> 16);
}
__device__ __forceinline__ float sigf(float x) {
    return 1.0f / (1.0f + __expf(-x));
}
__device__ __forceinline__ float tanhfast(float x) {
    return 1.0f - 2.0f / (__expf(2.0f * x) + 1.0f);
}
__device__ __forceinline__ floatx4 mfma16(shortx8 a, shortx8 b, floatx4 c) {
    return __builtin_amdgcn_mfma_f32_16x16x32_bf16(a, b, c, 0, 0, 0);
}

// ---------------------------------------------------------------------------
// Pre-pass: weights fp32 [out,in] -> bf16 MFMA fragments in d_ws.
// fi = ((d*64 + tile)*8 + ks)*64 + lane ; 8 bf16 each.
// tile 0..15 -> U_f cols; 16..31 -> I; 32..47 -> O; 48..63 -> U.
// elem e: k = ks*32 + (lane>>4)*8 + e, col = tile*16 + (lane&15)
// ---------------------------------------------------------------------------
__global__ void prep_weights(const float* __restrict__ U_f,
                             const float* __restrict__ U_iou,
                             unsigned short* __restrict__ wsB) {
    int idx = blockIdx.x * 256 + threadIdx.x;
    int lane = idx & 63;
    int ks   = (idx >> 6) & 7;
    int tile = (idx >> 9) & 63;
    int d    = idx >> 15;
    if (d >= NCH) return;
    int col = tile * 16 + (lane & 15);
    int k0  = ks * 32 + (lane >> 4) * 8;
    const float* src = (col < 256)
        ? (U_f   + (((size_t)d * 256 + col)         * 256 + k0))
        : (U_iou + (((size_t)d * 768 + (col - 256)) * 256 + k0));
    shortx8 o;
    #pragma unroll
    for (int e = 0; e < 8; ++e) o[e] = (short)f2bf(src[e]);
    reinterpret_cast<shortx8*>(wsB)[idx] = o;
}

// ---------------------------------------------------------------------------
// Main kernel, SWAPPED-OPERAND layout: D = mfma(W_frag, nh_frag) so the
// accumulator C/D maps thread (cl,g) -> node=cl(+nt*16), hidden cols
// g*4..g*4+3 (CONSECUTIVE) -> all elementwise work is float4 in registers.
// 512 thr (8 waves), BM=64 nodes, stage one child at a time (32 KiB LDS,
// 2 blocks/CU). Wave w owns hidden window [w*32, w*32+32): tiles
// F {2w,2w+1}, I/O/U {16/32/48 + 2w, +2w+1}. 2 barriers per child.
// LDS swizzle: [slot][ node ^ (slot&7) ][8] (round-4 verified, 0 conflicts).
// ---------------------------------------------------------------------------
__global__ __launch_bounds__(512, 4) void treelstm_main(
    const float* __restrict__ nh,       // [N][3][256]
    const float* __restrict__ ncc,      // [N][3][256]
    const float* __restrict__ f_in,     // [N][256]
    const float* __restrict__ iou_in,   // [N][768]
    const unsigned short* __restrict__ wsB,
    float* __restrict__ out)            // h [N][256] then c [N][256]
{
    __shared__ unsigned short sA[32 * BM * 8];   // 32 KiB: one child's nh tile

    const int tid  = threadIdx.x;
    const int nb   = blockIdx.x * BM;
    const int lane = tid & 63;
    const int w    = tid >> 6;        // 0..7 : hidden window [w*32, w*32+32)
    const int cl   = lane & 15;
    const int g    = lane >> 4;
    const int colb = w * 32 + g * 4;  // this thread's first hidden col

    const shortx8* Bfr = reinterpret_cast<const shortx8*>(wsB);

    floatx4 accIOU[2][3][4];   // [ch][gate I/O/U][nt] -- persistent
    floatx4 cagg[2][4];        // [ch][nt]
    floatx4 fin[2][4];
    #pragma unroll
    for (int ch = 0; ch < 2; ++ch)
        #pragma unroll
        for (int nt = 0; nt < 4; ++nt) {
            #pragma unroll
            for (int s = 0; s < 3; ++s)
                #pragma unroll
                for (int r = 0; r < 4; ++r) accIOU[ch][s][nt][r] = 0.0f;
            #pragma unroll
            for (int r = 0; r < 4; ++r) cagg[ch][nt][r] = 0.0f;
        }

    for (int d = 0; d < NCH; ++d) {
        if (d) __syncthreads();          // protect sA before overwrite
        // ---- stage child d: coalesced float4 reads, swizzled LDS writes ----
        #pragma unroll
        for (int i = 0; i < 4; ++i) {
            int c    = i * 512 + tid;    // 0..2047
            int node = c >> 5;
            int slot = c & 31;
            int gn   = nb + node;
            shortx8 o;
            if (gn < NNODES) {
                const float4* q = reinterpret_cast<const float4*>(
                    nh + ((size_t)gn * (NCH * HD) + d * HD + slot * 8));
                float4 u0 = q[0], u1 = q[1];
                o[0] = (short)f2bf(u0.x); o[1] = (short)f2bf(u0.y);
                o[2] = (short)f2bf(u0.z); o[3] = (short)f2bf(u0.w);
                o[4] = (short)f2bf(u1.x); o[5] = (short)f2bf(u1.y);
                o[6] = (short)f2bf(u1.z); o[7] = (short)f2bf(u1.w);
            } else {
                #pragma unroll
                for (int e = 0; e < 8; ++e) o[e] = 0;
            }
            int idx = slot * BM + (node ^ (slot & 7));
            *reinterpret_cast<shortx8*>(&sA[idx * 8]) = o;
        }
        __syncthreads();

        // ---- prefetch ncc (and f_in once): float4, node-major ----
        floatx4 ncr[2][4];
        #pragma unroll
        for (int ch = 0; ch < 2; ++ch)
            #pragma unroll
            for (int nt = 0; nt < 4; ++nt) {
                int n = nb + nt * 16 + cl;
                #pragma unroll
                for (int r = 0; r < 4; ++r) ncr[ch][nt][r] = 0.0f;
                if (n < NNODES) {
                    ncr[ch][nt] = *reinterpret_cast<const floatx4*>(
                        ncc + (size_t)n * (NCH * HD) + d * HD + colb + ch * 16);
                    if (d == 0)
                        fin[ch][nt] = *reinterpret_cast<const floatx4*>(
                            f_in + (size_t)n * HD + colb + ch * 16);
                } else if (d == 0) {
                    #pragma unroll
                    for (int r = 0; r < 4; ++r) fin[ch][nt][r] = 0.0f;
                }
            }

        // ---- unified K-loop: 8 weight tiles x 4 nh tiles per ks ----
        // aW[t]: t=0,1 -> F tiles 2w+t ; t=2+s*2+ch -> 16+s*16+2w+ch
        floatx4 accF[2][4];
        #pragma unroll
        for (int ch = 0; ch < 2; ++ch)
            #pragma unroll
            for (int nt = 0; nt < 4; ++nt)
                #pragma unroll
                for (int r = 0; r < 4; ++r) accF[ch][nt][r] = 0.0f;

        shortx8 aW[8], aWn[8];
        #pragma unroll
        for (int t = 0; t < 8; ++t) {
            int tile = (t < 2) ? (2 * w + t)
                               : (16 + ((t - 2) >> 1) * 16 + 2 * w + ((t - 2) & 1));
            aW[t] = Bfr[((d * 64 + tile) * 8 + 0) * 64 + lane];
        }
        #pragma unroll
        for (int ks = 0; ks < 8; ++ks) {
            if (ks < 7) {
                #pragma unroll
                for (int t = 0; t < 8; ++t) {
                    int tile = (t < 2) ? (2 * w + t)
                                       : (16 + ((t - 2) >> 1) * 16 + 2 * w + ((t - 2) & 1));
                    aWn[t] = Bfr[((d * 64 + tile) * 8 + ks + 1) * 64 + lane];
                }
            }
            int slot = ks * 4 + g;
            int x    = slot & 7;
            shortx8 bH[4];
            #pragma unroll
            for (int nt = 0; nt < 4; ++nt)
                bH[nt] = *reinterpret_cast<const shortx8*>(
                    &sA[(slot * BM + ((nt * 16 + cl) ^ x)) * 8]);
            #pragma unroll
            for (int ch = 0; ch < 2; ++ch)
                #pragma unroll
                for (int nt = 0; nt < 4; ++nt)
                    accF[ch][nt] = mfma16(aW[ch], bH[nt], accF[ch][nt]);
            #pragma unroll
            for (int s = 0; s < 3; ++s)
                #pragma unroll
                for (int ch = 0; ch < 2; ++ch)
                    #pragma unroll
                    for (int nt = 0; nt < 4; ++nt)
                        accIOU[ch][s][nt] =
                            mfma16(aW[2 + s * 2 + ch], bH[nt], accIOU[ch][s][nt]);
            if (ks < 7) {
                #pragma unroll
                for (int t = 0; t < 8; ++t) aW[t] = aWn[t];
            }
        }

        // ---- fold: cagg += sigmoid(F + f_in) * nc (all registers) ----
        #pragma unroll
        for (int ch = 0; ch < 2; ++ch)
            #pragma unroll
            for (int nt = 0; nt < 4; ++nt)
                #pragma unroll
                for (int r = 0; r < 4; ++r)
                    cagg[ch][nt][r] +=
                        sigf(accF[ch][nt][r] + fin[ch][nt][r]) * ncr[ch][nt][r];
    }

    // ---- epilogue: per-wave independent, all float4 ----
    #pragma unroll
    for (int ch = 0; ch < 2; ++ch)
        #pragma unroll
        for (int nt = 0; nt < 4; ++nt) {
            int n = nb + nt * 16 + cl;
            if (n >= NNODES) continue;
            size_t base = (size_t)n * 768 + colb + ch * 16;
            floatx4 i4 = *reinterpret_cast<const floatx4*>(iou_in + base);
            floatx4 o4 = *reinterpret_cast<const floatx4*>(iou_in + base + 256);
            floatx4 u4 = *reinterpret_cast<const floatx4*>(iou_in + base + 512);
            floatx4 cc, hh;
            #pragma unroll
            for (int r = 0; r < 4; ++r) {
                float iv = accIOU[ch][0][nt][r] + 2.0f * i4[r];
                float ov = accIOU[ch][1][nt][r] + 2.0f * o4[r];
                float uv = accIOU[ch][2][nt][r] + 2.0f * u4[r];
                float c  = sigf(iv) * tanhfast(uv) + cagg[ch][nt][r];
                cc[r] = c;
                hh[r] = sigf(ov) * tanhfast(c);
            }
            *reinterpret_cast<floatx4*>(
                out + (size_t)n * HD + colb + ch * 16) = hh;
            *reinterpret_cast<floatx4*>(
                out + (size_t)(NNODES + n) * HD + colb + ch * 16) = cc;
        }
}

extern "C" void kernel_launch(void* const* d_in, const int* in_sizes, int n_in,
                              void* d_out, int out_size, void* d_ws, size_t ws_size,
                              hipStream_t stream) {
    const float* nh     = (const float*)d_in[0];
    const float* ncc    = (const float*)d_in[1];
    const float* f_in   = (const float*)d_in[2];
    const float* iou_in = (const float*)d_in[3];
    const float* U_f    = (const float*)d_in[4];
    const float* U_iou  = (const float*)d_in[5];
    unsigned short* wsB = (unsigned short*)d_ws;

    if (ws_size < (size_t)(3 * 64 * 8 * 64) * 16) return;

    hipLaunchKernelGGL(prep_weights, dim3(384), dim3(256), 0, stream,
                       U_f, U_iou, wsB);
    hipLaunchKernelGGL(treelstm_main, dim3((NNODES + BM - 1) / BM), dim3(512),
                       0, stream, nh, ncc, f_in, iou_in, wsB, (float*)d_out);
}

// Round 6
// 832.138 us; speedup vs baseline: 1.7727x; 1.7727x over previous
//
#include <hip/hip_runtime.h>
#include <cstdint>
#include <cstddef>

#define NNODES 50000
#define HD 256
#define NCH 3
#define BM 32

typedef __attribute__((ext_vector_type(8))) short shortx8;
typedef __attribute__((ext_vector_type(4))) float floatx4;

__device__ __forceinline__ unsigned short f2bf(float x) {
    union { float f; uint32_t u; } v; v.f = x;
    uint32_t r = v.u + 0x7fffu + ((v.u >> 16) & 1u);   // RNE (weights, once)
    return (unsigned short)(r >> 16);
}
__device__ __forceinline__ unsigned short f2bf_fast(float x) {
    union { float f; uint32_t u; } v; v.f = x;          // round-nearest-ties-away
    return (unsigned short)((v.u + 0x8000u) >> 16);
}
__device__ __forceinline__ shortx8 cvt8(float4 a, float4 b) {
    shortx8 o;
    o[0] = (short)f2bf_fast(a.x); o[1] = (short)f2bf_fast(a.y);
    o[2] = (short)f2bf_fast(a.z); o[3] = (short)f2bf_fast(a.w);
    o[4] = (short)f2bf_fast(b.x); o[5] = (short)f2bf_fast(b.y);
    o[6] = (short)f2bf_fast(b.z); o[7] = (short)f2bf_fast(b.w);
    return o;
}
__device__ __forceinline__ float sigf(float x) {
    return 1.0f / (1.0f + __expf(-x));
}
__device__ __forceinline__ float tanhfast(float x) {
    return 1.0f - 2.0f / (__expf(2.0f * x) + 1.0f);
}
__device__ __forceinline__ floatx4 mfma16(shortx8 a, shortx8 b, floatx4 c) {
    return __builtin_amdgcn_mfma_f32_16x16x32_bf16(a, b, c, 0, 0, 0);
}

// ---------------------------------------------------------------------------
// Pre-pass: weights fp32 [out,in] -> bf16 MFMA fragments in d_ws.
// fi = ((d*64 + tile)*8 + ks)*64 + lane ; 8 bf16 each.
// tile 0..15 -> U_f cols; 16..31 -> I; 32..47 -> O; 48..63 -> U.
// elem e: k = ks*32 + (lane>>4)*8 + e, col = tile*16 + (lane&15)
// ---------------------------------------------------------------------------
__global__ void prep_weights(const float* __restrict__ U_f,
                             const float* __restrict__ U_iou,
                             unsigned short* __restrict__ wsB) {
    int idx = blockIdx.x * 256 + threadIdx.x;
    int lane = idx & 63;
    int ks   = (idx >> 6) & 7;
    int tile = (idx >> 9) & 63;
    int d    = idx >> 15;
    if (d >= NCH) return;
    int col = tile * 16 + (lane & 15);
    int k0  = ks * 32 + (lane >> 4) * 8;
    const float* src = (col < 256)
        ? (U_f   + (((size_t)d * 256 + col)         * 256 + k0))
        : (U_iou + (((size_t)d * 768 + (col - 256)) * 256 + k0));
    shortx8 o;
    #pragma unroll
    for (int e = 0; e < 8; ++e) o[e] = (short)f2bf(src[e]);
    reinterpret_cast<shortx8*>(wsB)[idx] = o;
}

// ---------------------------------------------------------------------------
// Main kernel, swapped-operand MFMA (D = W_frag x nh_frag), NO LDS, NO
// barriers. 1024 thr = 16 waves, BM=32 nodes. Wave w owns hidden cols
// [w*16, w*16+16): tiles {w, 16+w, 32+w, 48+w}. Thread (cl,g) holds
// node = nb + nt*16 + cl, cols w*16 + g*4 .. +3 -> float4 global access
// everywhere. nh B-frag = 32B contiguous global read (16 full lines per
// wave-instr), shared across the block's 16 waves via L1/L2.
// Persistent regs/thread: accI/O/U 24 + cagg 8 + fin 8 = 40 floats.
// Tail: clamped addresses, guarded stores (garbage lanes never stored).
// ---------------------------------------------------------------------------
__global__ __launch_bounds__(1024, 4) void treelstm_main(
    const float* __restrict__ nh,       // [N][3][256]
    const float* __restrict__ ncc,      // [N][3][256]
    const float* __restrict__ f_in,     // [N][256]
    const float* __restrict__ iou_in,   // [N][768]
    const unsigned short* __restrict__ wsB,
    float* __restrict__ out)            // h [N][256] then c [N][256]
{
    const int tid  = threadIdx.x;
    const int nb   = blockIdx.x * BM;
    const int lane = tid & 63;
    const int w    = tid >> 6;        // 0..15: hidden window [w*16, w*16+16)
    const int cl   = lane & 15;
    const int g    = lane >> 4;
    const int colb = w * 16 + g * 4;  // this thread's 4 consecutive cols

    const shortx8* Bfr = reinterpret_cast<const shortx8*>(wsB);

    const int  n0  = nb + cl;                    // always < NNODES
    const int  n1  = nb + 16 + cl;
    const bool v1  = (n1 < NNODES);
    const int  n1c = v1 ? n1 : n0;               // clamped (avoid OOB)

    floatx4 accI[2], accO[2], accU[2], cagg[2], fin[2];
    #pragma unroll
    for (int nt = 0; nt < 2; ++nt)
        #pragma unroll
        for (int r = 0; r < 4; ++r) {
            accI[nt][r] = 0.0f; accO[nt][r] = 0.0f;
            accU[nt][r] = 0.0f; cagg[nt][r] = 0.0f;
        }

    fin[0] = *reinterpret_cast<const floatx4*>(f_in + (size_t)n0  * HD + colb);
    fin[1] = *reinterpret_cast<const floatx4*>(f_in + (size_t)n1c * HD + colb);

    #pragma unroll 1
    for (int d = 0; d < NCH; ++d) {
        floatx4 ncr[2];
        ncr[0] = *reinterpret_cast<const floatx4*>(
            ncc + (size_t)n0  * (NCH * HD) + d * HD + colb);
        ncr[1] = *reinterpret_cast<const floatx4*>(
            ncc + (size_t)n1c * (NCH * HD) + d * HD + colb);

        floatx4 accF[2];
        #pragma unroll
        for (int nt = 0; nt < 2; ++nt)
            #pragma unroll
            for (int r = 0; r < 4; ++r) accF[nt][r] = 0.0f;

        const float* base0 = nh + (size_t)n0  * (NCH * HD) + d * HD + g * 8;
        const float* base1 = nh + (size_t)n1c * (NCH * HD) + d * HD + g * 8;

        #pragma unroll
        for (int ks = 0; ks < 8; ++ks) {
            // nh B-fragments: 32B contiguous per lane
            float4 q0a = *reinterpret_cast<const float4*>(base0 + ks * 32);
            float4 q0b = *reinterpret_cast<const float4*>(base0 + ks * 32 + 4);
            float4 q1a = *reinterpret_cast<const float4*>(base1 + ks * 32);
            float4 q1b = *reinterpret_cast<const float4*>(base1 + ks * 32 + 4);
            shortx8 b0 = cvt8(q0a, q0b);
            shortx8 b1 = cvt8(q1a, q1b);
            // weight A-fragments (L1/L2 resident)
            shortx8 aF = Bfr[((d * 64 +      w) * 8 + ks) * 64 + lane];
            shortx8 aI = Bfr[((d * 64 + 16 + w) * 8 + ks) * 64 + lane];
            shortx8 aO = Bfr[((d * 64 + 32 + w) * 8 + ks) * 64 + lane];
            shortx8 aU = Bfr[((d * 64 + 48 + w) * 8 + ks) * 64 + lane];
            __builtin_amdgcn_s_setprio(1);
            accF[0] = mfma16(aF, b0, accF[0]);
            accF[1] = mfma16(aF, b1, accF[1]);
            accI[0] = mfma16(aI, b0, accI[0]);
            accI[1] = mfma16(aI, b1, accI[1]);
            accO[0] = mfma16(aO, b0, accO[0]);
            accO[1] = mfma16(aO, b1, accO[1]);
            accU[0] = mfma16(aU, b0, accU[0]);
            accU[1] = mfma16(aU, b1, accU[1]);
            __builtin_amdgcn_s_setprio(0);
        }

        // fold: cagg += sigmoid(F + f_in) * nc   (all registers, float4)
        #pragma unroll
        for (int nt = 0; nt < 2; ++nt)
            #pragma unroll
            for (int r = 0; r < 4; ++r)
                cagg[nt][r] += sigf(accF[nt][r] + fin[nt][r]) * ncr[nt][r];
    }

    // ---- epilogue: per-thread float4, no syncs ----
    #pragma unroll
    for (int nt = 0; nt < 2; ++nt) {
        if (nt == 1 && !v1) continue;
        int n = (nt == 0) ? n0 : n1;
        size_t base = (size_t)n * 768 + colb;
        floatx4 i4 = *reinterpret_cast<const floatx4*>(iou_in + base);
        floatx4 o4 = *reinterpret_cast<const floatx4*>(iou_in + base + 256);
        floatx4 u4 = *reinterpret_cast<const floatx4*>(iou_in + base + 512);
        floatx4 cc, hh;
        #pragma unroll
        for (int r = 0; r < 4; ++r) {
            float iv = accI[nt][r] + 2.0f * i4[r];
            float ov = accO[nt][r] + 2.0f * o4[r];
            float uv = accU[nt][r] + 2.0f * u4[r];
            float c  = sigf(iv) * tanhfast(uv) + cagg[nt][r];
            cc[r] = c;
            hh[r] = sigf(ov) * tanhfast(c);
        }
        *reinterpret_cast<floatx4*>(out + (size_t)n * HD + colb) = hh;
        *reinterpret_cast<floatx4*>(out + (size_t)(NNODES + n) * HD + colb) = cc;
    }
}

extern "C" void kernel_launch(void* const* d_in, const int* in_sizes, int n_in,
                              void* d_out, int out_size, void* d_ws, size_t ws_size,
                              hipStream_t stream) {
    const float* nh     = (const float*)d_in[0];
    const float* ncc    = (const float*)d_in[1];
    const float* f_in   = (const float*)d_in[2];
    const float* iou_in = (const float*)d_in[3];
    const float* U_f    = (const float*)d_in[4];
    const float* U_iou  = (const float*)d_in[5];
    unsigned short* wsB = (unsigned short*)d_ws;

    if (ws_size < (size_t)(3 * 64 * 8 * 64) * 16) return;

    hipLaunchKernelGGL(prep_weights, dim3(384), dim3(256), 0, stream,
                       U_f, U_iou, wsB);
    hipLaunchKernelGGL(treelstm_main, dim3((NNODES + BM - 1) / BM), dim3(1024),
                       0, stream, nh, ncc, f_in, iou_in, wsB, (float*)d_out);
}

// Round 7
// 342.330 us; speedup vs baseline: 4.3090x; 2.4308x over previous
//
#include <hip/hip_runtime.h>
#include <cstdint>
#include <cstddef>

#define NNODES 50000
#define HD 256
#define NCH 3
#define BM 32

typedef __attribute__((ext_vector_type(8))) short shortx8;
typedef __attribute__((ext_vector_type(4))) float floatx4;

__device__ __forceinline__ unsigned short f2bf(float x) {
    union { float f; uint32_t u; } v; v.f = x;
    uint32_t r = v.u + 0x7fffu + ((v.u >> 16) & 1u);   // RNE
    return (unsigned short)(r >> 16);
}
__device__ __forceinline__ shortx8 cvt8(float4 a, float4 b) {
    shortx8 o;
    o[0] = (short)f2bf(a.x); o[1] = (short)f2bf(a.y);
    o[2] = (short)f2bf(a.z); o[3] = (short)f2bf(a.w);
    o[4] = (short)f2bf(b.x); o[5] = (short)f2bf(b.y);
    o[6] = (short)f2bf(b.z); o[7] = (short)f2bf(b.w);
    return o;
}
__device__ __forceinline__ float sigf(float x) {
    return 1.0f / (1.0f + __expf(-x));
}
__device__ __forceinline__ float tanhfast(float x) {
    return 1.0f - 2.0f / (__expf(2.0f * x) + 1.0f);
}
__device__ __forceinline__ floatx4 mfma16(shortx8 a, shortx8 b, floatx4 c) {
    return __builtin_amdgcn_mfma_f32_16x16x32_bf16(a, b, c, 0, 0, 0);
}

// ---------------------------------------------------------------------------
// Pre-pass: weights fp32 [out,in] -> bf16 MFMA fragments in d_ws.
// fi = ((d*64 + tile)*8 + ks)*64 + lane ; 8 bf16 each.
// tile 0..15 -> U_f cols; 16..31 -> I; 32..47 -> O; 48..63 -> U.
// elem e: k = ks*32 + (lane>>4)*8 + e, col = tile*16 + (lane&15)
// ---------------------------------------------------------------------------
__global__ void prep_weights(const float* __restrict__ U_f,
                             const float* __restrict__ U_iou,
                             unsigned short* __restrict__ wsB) {
    int idx = blockIdx.x * 256 + threadIdx.x;
    int lane = idx & 63;
    int ks   = (idx >> 6) & 7;
    int tile = (idx >> 9) & 63;
    int d    = idx >> 15;
    if (d >= NCH) return;
    int col = tile * 16 + (lane & 15);
    int k0  = ks * 32 + (lane >> 4) * 8;
    const float* src = (col < 256)
        ? (U_f   + (((size_t)d * 256 + col)         * 256 + k0))
        : (U_iou + (((size_t)d * 768 + (col - 256)) * 256 + k0));
    shortx8 o;
    #pragma unroll
    for (int e = 0; e < 8; ++e) o[e] = (short)f2bf(src[e]);
    reinterpret_cast<shortx8*>(wsB)[idx] = o;
}

// ---------------------------------------------------------------------------
// Main kernel: swapped-operand MFMA (D = W_frag x nh_frag) so thread (cl,g)
// holds node = nt*16+cl, output cols tile*16 + g*4..+3 (float4-aligned in
// global). 512 thr = 8 waves, BM=32. Stage all 3 children's nh into 48 KiB
// swizzled LDS, ONE barrier, then each wave free-runs its 32 hidden cols:
// per child {F pass + fold}, 3 gate passes (I,O,U), register epilogue.
// Register budget: persistent 80 floats, peak ~110 -> fits 128 cap
// (launch_bounds 512,4 -> 2 blocks/CU). K-loops split per gate and
// unroll 2 only, to prevent the r5/r6 unroll-hoist spill.
// LDS: [d][node][slot ^ (node&7)][8] -> conflict-free writes, 2-way reads.
// ---------------------------------------------------------------------------
__global__ __launch_bounds__(512, 4) void treelstm_main(
    const float* __restrict__ nh,       // [N][3][256]
    const float* __restrict__ ncc,      // [N][3][256]
    const float* __restrict__ f_in,     // [N][256]
    const float* __restrict__ iou_in,   // [N][768]
    const unsigned short* __restrict__ wsB,
    float* __restrict__ out)            // h [N][256] then c [N][256]
{
    __shared__ unsigned short sA[NCH * BM * 32 * 8];   // 48 KiB

    const int tid  = threadIdx.x;
    const int nb   = blockIdx.x * BM;
    const int lane = tid & 63;
    const int w    = tid >> 6;        // 0..7: hidden cols [w*32, w*32+32)
    const int cl   = lane & 15;
    const int g    = lane >> 4;

    const shortx8* Bfr = reinterpret_cast<const shortx8*>(wsB);

    // ---- stage all 3 children: coalesced reads, swizzled LDS writes ----
    #pragma unroll
    for (int i = 0; i < 6; ++i) {
        int c    = i * 512 + tid;         // 0..3071
        int d    = c >> 10;
        int node = (c >> 5) & 31;
        int slot = c & 31;
        int gn   = nb + node;
        shortx8 o;
        if (gn < NNODES) {
            const float4* q = reinterpret_cast<const float4*>(
                nh + ((size_t)gn * (NCH * HD) + d * HD + slot * 8));
            o = cvt8(q[0], q[1]);
        } else {
            #pragma unroll
            for (int e = 0; e < 8; ++e) o[e] = 0;
        }
        int idx = (d * BM + node) * 32 + (slot ^ (node & 7));
        *reinterpret_cast<shortx8*>(&sA[idx * 8]) = o;
    }
    __syncthreads();          // the ONLY barrier

    const int  n0  = nb + cl;
    const int  n1  = nb + 16 + cl;
    const bool v1  = (n1 < NNODES);
    const int  n1c = v1 ? n1 : n0;

    // per-thread cols: j tile -> col = w*32 + j*16 + g*4
    const int c0 = w * 32 + g * 4;        // j=0
    // f_in persistent
    floatx4 fin[2][2];        // [j][nt]
    fin[0][0] = *reinterpret_cast<const floatx4*>(f_in + (size_t)n0  * HD + c0);
    fin[1][0] = *reinterpret_cast<const floatx4*>(f_in + (size_t)n0  * HD + c0 + 16);
    fin[0][1] = *reinterpret_cast<const floatx4*>(f_in + (size_t)n1c * HD + c0);
    fin[1][1] = *reinterpret_cast<const floatx4*>(f_in + (size_t)n1c * HD + c0 + 16);

    floatx4 cagg[2][2];
    floatx4 accIOU[3][2][2];  // [gate s][j][nt] persistent
    #pragma unroll
    for (int j = 0; j < 2; ++j)
        #pragma unroll
        for (int nt = 0; nt < 2; ++nt) {
            #pragma unroll
            for (int r = 0; r < 4; ++r) cagg[j][nt][r] = 0.0f;
            #pragma unroll
            for (int s = 0; s < 3; ++s)
                #pragma unroll
                for (int r = 0; r < 4; ++r) accIOU[s][j][nt][r] = 0.0f;
        }

    const int xr = cl & 7;    // read swizzle (same for node cl and 16+cl)

    #pragma unroll 1
    for (int d = 0; d < NCH; ++d) {
        // ncc prefetch (hides under F pass)
        floatx4 ncr[2][2];
        ncr[0][0] = *reinterpret_cast<const floatx4*>(
            ncc + (size_t)n0  * (NCH * HD) + d * HD + c0);
        ncr[1][0] = *reinterpret_cast<const floatx4*>(
            ncc + (size_t)n0  * (NCH * HD) + d * HD + c0 + 16);
        ncr[0][1] = *reinterpret_cast<const floatx4*>(
            ncc + (size_t)n1c * (NCH * HD) + d * HD + c0);
        ncr[1][1] = *reinterpret_cast<const floatx4*>(
            ncc + (size_t)n1c * (NCH * HD) + d * HD + c0 + 16);

        // ---- F pass ----
        floatx4 accF[2][2];
        #pragma unroll
        for (int j = 0; j < 2; ++j)
            #pragma unroll
            for (int nt = 0; nt < 2; ++nt)
                #pragma unroll
                for (int r = 0; r < 4; ++r) accF[j][nt][r] = 0.0f;

        #pragma unroll 2
        for (int ks = 0; ks < 8; ++ks) {
            shortx8 a0 = Bfr[((d * 64 + 2 * w)     * 8 + ks) * 64 + lane];
            shortx8 a1 = Bfr[((d * 64 + 2 * w + 1) * 8 + ks) * 64 + lane];
            int sl = (ks * 4 + g) ^ xr;
            shortx8 b0 = *reinterpret_cast<const shortx8*>(
                &sA[((d * BM + cl)      * 32 + sl) * 8]);
            shortx8 b1 = *reinterpret_cast<const shortx8*>(
                &sA[((d * BM + 16 + cl) * 32 + sl) * 8]);
            accF[0][0] = mfma16(a0, b0, accF[0][0]);
            accF[0][1] = mfma16(a0, b1, accF[0][1]);
            accF[1][0] = mfma16(a1, b0, accF[1][0]);
            accF[1][1] = mfma16(a1, b1, accF[1][1]);
        }
        // fold
        #pragma unroll
        for (int j = 0; j < 2; ++j)
            #pragma unroll
            for (int nt = 0; nt < 2; ++nt)
                #pragma unroll
                for (int r = 0; r < 4; ++r)
                    cagg[j][nt][r] +=
                        sigf(accF[j][nt][r] + fin[j][nt][r]) * ncr[j][nt][r];

        // ---- IOU gate passes ----
        #pragma unroll
        for (int s = 0; s < 3; ++s) {
            #pragma unroll 2
            for (int ks = 0; ks < 8; ++ks) {
                shortx8 a0 = Bfr[((d * 64 + 16 + s * 16 + 2 * w)     * 8 + ks) * 64 + lane];
                shortx8 a1 = Bfr[((d * 64 + 16 + s * 16 + 2 * w + 1) * 8 + ks) * 64 + lane];
                int sl = (ks * 4 + g) ^ xr;
                shortx8 b0 = *reinterpret_cast<const shortx8*>(
                    &sA[((d * BM + cl)      * 32 + sl) * 8]);
                shortx8 b1 = *reinterpret_cast<const shortx8*>(
                    &sA[((d * BM + 16 + cl) * 32 + sl) * 8]);
                accIOU[s][0][0] = mfma16(a0, b0, accIOU[s][0][0]);
                accIOU[s][0][1] = mfma16(a0, b1, accIOU[s][0][1]);
                accIOU[s][1][0] = mfma16(a1, b0, accIOU[s][1][0]);
                accIOU[s][1][1] = mfma16(a1, b1, accIOU[s][1][1]);
            }
        }
    }

    // ---- epilogue: per-thread float4, no syncs ----
    #pragma unroll
    for (int nt = 0; nt < 2; ++nt) {
        if (nt == 1 && !v1) continue;
        int n = (nt == 0) ? n0 : n1;
        #pragma unroll
        for (int j = 0; j < 2; ++j) {
            int col = c0 + j * 16;
            size_t base = (size_t)n * 768 + col;
            floatx4 i4 = *reinterpret_cast<const floatx4*>(iou_in + base);
            floatx4 o4 = *reinterpret_cast<const floatx4*>(iou_in + base + 256);
            floatx4 u4 = *reinterpret_cast<const floatx4*>(iou_in + base + 512);
            floatx4 cc, hh;
            #pragma unroll
            for (int r = 0; r < 4; ++r) {
                float iv = accIOU[0][j][nt][r] + 2.0f * i4[r];
                float ov = accIOU[1][j][nt][r] + 2.0f * o4[r];
                float uv = accIOU[2][j][nt][r] + 2.0f * u4[r];
                float c  = sigf(iv) * tanhfast(uv) + cagg[j][nt][r];
                cc[r] = c;
                hh[r] = sigf(ov) * tanhfast(c);
            }
            *reinterpret_cast<floatx4*>(out + (size_t)n * HD + col) = hh;
            *reinterpret_cast<floatx4*>(out + (size_t)(NNODES + n) * HD + col) = cc;
        }
    }
}

extern "C" void kernel_launch(void* const* d_in, const int* in_sizes, int n_in,
                              void* d_out, int out_size, void* d_ws, size_t ws_size,
                              hipStream_t stream) {
    const float* nh     = (const float*)d_in[0];
    const float* ncc    = (const float*)d_in[1];
    const float* f_in   = (const float*)d_in[2];
    const float* iou_in = (const float*)d_in[3];
    const float* U_f    = (const float*)d_in[4];
    const float* U_iou  = (const float*)d_in[5];
    unsigned short* wsB = (unsigned short*)d_ws;

    if (ws_size < (size_t)(3 * 64 * 8 * 64) * 16) return;

    hipLaunchKernelGGL(prep_weights, dim3(384), dim3(256), 0, stream,
                       U_f, U_iou, wsB);
    hipLaunchKernelGGL(treelstm_main, dim3((NNODES + BM - 1) / BM), dim3(512),
                       0, stream, nh, ncc, f_in, iou_in, wsB, (float*)d_out);
}

// Round 8
// 283.464 us; speedup vs baseline: 5.2039x; 1.2077x over previous
//
#include <hip/hip_runtime.h>
#include <cstdint>
#include <cstddef>

#define NNODES 50000
#define HD 256
#define NCH 3
#define BM 32

typedef __attribute__((ext_vector_type(8))) short shortx8;
typedef __attribute__((ext_vector_type(4))) float floatx4;
typedef __attribute__((ext_vector_type(16))) float floatx16;

__device__ __forceinline__ unsigned short f2bf(float x) {
    union { float f; uint32_t u; } v; v.f = x;
    uint32_t r = v.u + 0x7fffu + ((v.u >> 16) & 1u);   // RNE
    return (unsigned short)(r >> 16);
}
__device__ __forceinline__ float bf2f(unsigned short u) {
    union { uint32_t u; float f; } v; v.u = ((uint32_t)u) << 16; return v.f;
}
__device__ __forceinline__ shortx8 cvt8(float4 a, float4 b) {
    shortx8 o;
    o[0] = (short)f2bf(a.x); o[1] = (short)f2bf(a.y);
    o[2] = (short)f2bf(a.z); o[3] = (short)f2bf(a.w);
    o[4] = (short)f2bf(b.x); o[5] = (short)f2bf(b.y);
    o[6] = (short)f2bf(b.z); o[7] = (short)f2bf(b.w);
    return o;
}
__device__ __forceinline__ float sigf(float x) {
    return 1.0f / (1.0f + __expf(-x));
}
__device__ __forceinline__ float tanhfast(float x) {
    return 1.0f - 2.0f / (__expf(2.0f * x) + 1.0f);
}
__device__ __forceinline__ floatx16 mfma32(shortx8 a, shortx8 b, floatx16 c) {
    return __builtin_amdgcn_mfma_f32_32x32x16_bf16(a, b, c, 0, 0, 0);
}

// ---------------------------------------------------------------------------
// Pre-pass: weights fp32 [out,in] -> bf16 fragments for 32x32x16 MFMA.
// fi = ((d*32 + tile)*16 + ks)*64 + lane ; 8 bf16 each.
// tile 0..7 -> U_f cols; 8..15 -> I; 16..23 -> O; 24..31 -> U (32-wide tiles)
// lane l: wcol = tile*32 + (l&31), k = ks*16 + (l>>5)*8 + e
// ---------------------------------------------------------------------------
__global__ void prep_weights32(const float* __restrict__ U_f,
                               const float* __restrict__ U_iou,
                               unsigned short* __restrict__ wsB) {
    int idx = blockIdx.x * 256 + threadIdx.x;   // 98304 frags
    int lane = idx & 63;
    int ks   = (idx >> 6) & 15;
    int tile = (idx >> 10) & 31;
    int d    = idx >> 15;
    if (d >= NCH) return;
    int col = tile * 32 + (lane & 31);
    int k0  = ks * 16 + (lane >> 5) * 8;
    const float* src = (col < 256)
        ? (U_f   + (((size_t)d * 256 + col)         * 256 + k0))
        : (U_iou + (((size_t)d * 768 + (col - 256)) * 256 + k0));
    shortx8 o;
    #pragma unroll
    for (int e = 0; e < 8; ++e) o[e] = (short)f2bf(src[e]);
    reinterpret_cast<shortx8*>(wsB)[idx] = o;
}

// ---------------------------------------------------------------------------
// Main kernel: mfma_f32_32x32x16_bf16, A = weight tile (M=32 wcols),
// B = nh (N=32 nodes). C/D: lane holds node = lane&31, 16 wcols =
// cg*32 + 4*(lane>>5) + 8q + r  (4 float4-aligned quads) -> all
// elementwise work is register float4.
// 512 thr = 8 waves, BM=32 nodes/block, wave w = col-group (32 wcols).
// 48 KiB LDS (3 children nh, 16B-chunk XOR swizzle), ONE barrier,
// 2 blocks/CU. Per k-step: 4 weight L2 loads + 1 LDS read + 4 MFMAs.
// LDS: chunk' = chunk ^ (node&7) -> conflict-free writes AND reads.
// ---------------------------------------------------------------------------
__global__ __launch_bounds__(512, 4) void treelstm_main(
    const float* __restrict__ nh,       // [N][3][256]
    const float* __restrict__ ncc,      // [N][3][256]
    const float* __restrict__ f_in,     // [N][256]
    const float* __restrict__ iou_in,   // [N][768]
    const unsigned short* __restrict__ wsB,
    float* __restrict__ out)            // h [N][256] then c [N][256]
{
    __shared__ unsigned short sA[NCH * BM * 32 * 8];   // 48 KiB

    const int tid  = threadIdx.x;
    const int nb   = blockIdx.x * BM;
    const int lane = tid & 63;
    const int cg   = tid >> 6;        // wave = col group, cols [cg*32, +32)
    const int nl   = lane & 31;       // this thread's node (one node!)
    const int hi   = lane >> 5;
    const int colb = cg * 32 + hi * 4;   // cols colb + 8q + r

    const shortx8* Bfr = reinterpret_cast<const shortx8*>(wsB);

    // ---- stage all 3 children's nh: coalesced reads, swizzled chunks ----
    #pragma unroll
    for (int i = 0; i < 6; ++i) {
        int c    = i * 512 + tid;        // 0..3071
        int d    = c >> 10;
        int node = (c >> 5) & 31;
        int slot = c & 31;
        int gn   = nb + node;
        shortx8 o;
        if (gn < NNODES) {
            const float4* q = reinterpret_cast<const float4*>(
                nh + ((size_t)gn * (NCH * HD) + d * HD + slot * 8));
            o = cvt8(q[0], q[1]);
        } else {
            #pragma unroll
            for (int e = 0; e < 8; ++e) o[e] = 0;
        }
        int idx = (d * BM + node) * 32 + (slot ^ (node & 7));
        *reinterpret_cast<shortx8*>(&sA[idx * 8]) = o;
    }
    __syncthreads();          // the ONLY barrier

    const int  n     = nb + nl;
    const bool valid = (n < NNODES);
    const int  nc_   = valid ? n : (NNODES - 1);

    // f_in packed to bf16 (8 regs persistent)
    ushort4 finb[4];
    #pragma unroll
    for (int q = 0; q < 4; ++q) {
        floatx4 v = *reinterpret_cast<const floatx4*>(
            f_in + (size_t)nc_ * HD + colb + q * 8);
        finb[q] = ushort4{f2bf(v[0]), f2bf(v[1]), f2bf(v[2]), f2bf(v[3])};
    }

    float cagg[16];
    #pragma unroll
    for (int t = 0; t < 16; ++t) cagg[t] = 0.0f;

    floatx16 accI, accO, accU;
    #pragma unroll
    for (int t = 0; t < 16; ++t) { accI[t] = 0.0f; accO[t] = 0.0f; accU[t] = 0.0f; }

    const int nsw = nl & 7;   // chunk swizzle for this thread's node row

    #pragma unroll 1
    for (int d = 0; d < NCH; ++d) {
        floatx16 accF;
        #pragma unroll
        for (int t = 0; t < 16; ++t) accF[t] = 0.0f;

        #pragma unroll 2
        for (int ks = 0; ks < 16; ++ks) {
            shortx8 aF = Bfr[((d * 32 +      cg) * 16 + ks) * 64 + lane];
            shortx8 aI = Bfr[((d * 32 +  8 + cg) * 16 + ks) * 64 + lane];
            shortx8 aO = Bfr[((d * 32 + 16 + cg) * 16 + ks) * 64 + lane];
            shortx8 aU = Bfr[((d * 32 + 24 + cg) * 16 + ks) * 64 + lane];
            int ch = (ks * 2 + hi) ^ nsw;
            shortx8 b = *reinterpret_cast<const shortx8*>(
                &sA[((d * BM + nl) * 32 + ch) * 8]);
            accF = mfma32(aF, b, accF);
            accI = mfma32(aI, b, accI);
            accO = mfma32(aO, b, accO);
            accU = mfma32(aU, b, accU);
        }

        // ---- fold: cagg += sigmoid(F + f_in) * nc  (registers, float4) ----
        #pragma unroll
        for (int q = 0; q < 4; ++q) {
            floatx4 ncr = *reinterpret_cast<const floatx4*>(
                ncc + (size_t)nc_ * (NCH * HD) + d * HD + colb + q * 8);
            cagg[q * 4 + 0] += sigf(accF[q * 4 + 0] + bf2f(finb[q].x)) * ncr[0];
            cagg[q * 4 + 1] += sigf(accF[q * 4 + 1] + bf2f(finb[q].y)) * ncr[1];
            cagg[q * 4 + 2] += sigf(accF[q * 4 + 2] + bf2f(finb[q].z)) * ncr[2];
            cagg[q * 4 + 3] += sigf(accF[q * 4 + 3] + bf2f(finb[q].w)) * ncr[3];
        }
    }

    // ---- epilogue: one node per thread, 4 float4 quads, no syncs ----
    if (valid) {
        #pragma unroll
        for (int q = 0; q < 4; ++q) {
            int col = colb + q * 8;
            size_t base = (size_t)n * 768 + col;
            floatx4 i4 = *reinterpret_cast<const floatx4*>(iou_in + base);
            floatx4 o4 = *reinterpret_cast<const floatx4*>(iou_in + base + 256);
            floatx4 u4 = *reinterpret_cast<const floatx4*>(iou_in + base + 512);
            floatx4 cc, hh;
            #pragma unroll
            for (int r = 0; r < 4; ++r) {
                int t = q * 4 + r;
                float iv = accI[t] + 2.0f * i4[r];
                float ov = accO[t] + 2.0f * o4[r];
                float uv = accU[t] + 2.0f * u4[r];
                float c  = sigf(iv) * tanhfast(uv) + cagg[t];
                cc[r] = c;
                hh[r] = sigf(ov) * tanhfast(c);
            }
            *reinterpret_cast<floatx4*>(out + (size_t)n * HD + col) = hh;
            *reinterpret_cast<floatx4*>(out + (size_t)(NNODES + n) * HD + col) = cc;
        }
    }
}

extern "C" void kernel_launch(void* const* d_in, const int* in_sizes, int n_in,
                              void* d_out, int out_size, void* d_ws, size_t ws_size,
                              hipStream_t stream) {
    const float* nh     = (const float*)d_in[0];
    const float* ncc    = (const float*)d_in[1];
    const float* f_in   = (const float*)d_in[2];
    const float* iou_in = (const float*)d_in[3];
    const float* U_f    = (const float*)d_in[4];
    const float* U_iou  = (const float*)d_in[5];
    unsigned short* wsB = (unsigned short*)d_ws;

    if (ws_size < (size_t)(3 * 32 * 16 * 64) * 16) return;

    hipLaunchKernelGGL(prep_weights32, dim3(384), dim3(256), 0, stream,
                       U_f, U_iou, wsB);
    hipLaunchKernelGGL(treelstm_main, dim3((NNODES + BM - 1) / BM), dim3(512),
                       0, stream, nh, ncc, f_in, iou_in, wsB, (float*)d_out);
}